// Round 5
// baseline (26.248 us; speedup 1.0000x reference)
//
#include <hip/hip_runtime.h>
#include <math.h>

// Problem constants (from reference): T=26246, B=128, IN=6, H=1.
#define T_LEN 26246
#define B_SZ  128
// 2*log2(e): tanh(z) = 1 - 2/(2^(SCALE*z) + 1)
#define SCALE 2.88539008177792681472f

#define CHUNK 52     // output steps per block
#define G     8      // steps per staged group
#define NCH   ((T_LEN + CHUNK - 1) / CHUNK)       // 505 blocks ~ 1.97/CU
#define TOTAL_F4 ((size_t)T_LEN * 192)            // total float4 in x (T*128*6/4)

// Compile-time component pick from float4 xr[12] (indices constant after unroll).
#define XF(n) (((n) & 3) == 0 ? xr[(n) >> 2].x : \
               ((n) & 3) == 1 ? xr[(n) >> 2].y : \
               ((n) & 3) == 2 ? xr[(n) >> 2].z : xr[(n) >> 2].w)

// One fused kernel. Each block owns output rows [t0, t0+CHUNK), starting warm
// steps early from h=0 (contraction: |dh_t/dh_{t-1}| <= |w|, so truncated
// history error <= |w|^warm <= 1e-4).
//
// Staging: per 8-step group the block's x span is 24576B contiguous and
// 16B-aligned. 128 threads load 12 float4 each (fully coalesced), compute the
// 6-wide input projection for 8 complete (t,b) rows in registers, and store
// 8 floats of a = SCALE*(x·W_ih + b_ih + b_hh) to a double-buffered LDS tile.
// The scan lane (lane=batch) then reads one conflict-free ds_read_b32/step.
__global__ __launch_bounds__(128) void rnn_scan_fused(
    const float* __restrict__ x, const float* __restrict__ W_ih,
    const float* __restrict__ W_hh, const float* __restrict__ b_ih,
    const float* __restrict__ b_hh, const float* __restrict__ fc_w,
    const float* __restrict__ fc_b, float* __restrict__ out) {
  const int b  = threadIdx.x;           // lane role: batch element
  const int k  = threadIdx.x;           // staging role: row-octet owner
  const int t0 = blockIdx.x * CHUNK;

  __shared__ float a_lds[2][G * B_SZ];  // 2 x 4KB

  const float w  = W_hh[0];
  const float w2 = SCALE * w;
  const float s0 = SCALE * W_ih[0], s1 = SCALE * W_ih[1], s2 = SCALE * W_ih[2],
              s3 = SCALE * W_ih[3], s4 = SCALE * W_ih[4], s5 = SCALE * W_ih[5];
  const float sb = SCALE * (b_ih[0] + b_hh[0]);
  const float fw = fc_w[0], fb = fc_b[0];

  // Adaptive warm-up: |w|^warm <= 1e-4.
  int warm = 16;                        // 0.56^16 ~ 9e-5
  {
    float aw = fabsf(w);
    if (aw > 0.56f) {
      float l = logf(fminf(aw, 0.999f));
      warm = (int)ceilf(-9.2103404f / l);
      if (warm > 2048) warm = 2048;
    }
  }
  int tw = t0 - warm;
  if (tw < 0) tw = 0;
  const int steps   = t0 + CHUNK - tw;
  const int ngroups = (steps + G - 1) / G;

  float4 xr[12];

  // Coalesced load of one group's x span (8 steps, clamped at the end).
  auto LOADX = [&](int tg) {
    size_t base = (size_t)tg * 192 + 12 * (size_t)k;
    #pragma unroll
    for (int i = 0; i < 12; ++i) {
      size_t idx = base + i;
      if (idx >= TOTAL_F4) idx = TOTAL_F4 - 1;
      xr[i] = ((const float4*)x)[idx];
    }
  };

  // Project 8 rows held in xr, store to LDS buffer `cur`.
  auto PROJ = [&](int cur) {
    float av[G];
    #pragma unroll
    for (int e = 0; e < G; ++e) {
      float a = fmaf(XF(6 * e + 0), s0, sb);
      a = fmaf(XF(6 * e + 1), s1, a);
      a = fmaf(XF(6 * e + 2), s2, a);
      a = fmaf(XF(6 * e + 3), s3, a);
      a = fmaf(XF(6 * e + 4), s4, a);
      a = fmaf(XF(6 * e + 5), s5, a);
      av[e] = a;
    }
    float4* dst = (float4*)&a_lds[cur][8 * k];
    dst[0] = make_float4(av[0], av[1], av[2], av[3]);
    dst[1] = make_float4(av[4], av[5], av[6], av[7]);
  };

  // Prologue: fill buffer 0, issue loads for group 1.
  LOADX(tw);
  PROJ(0);
  LOADX(tw + G);
  __syncthreads();

  float h = 0.0f;
  int cur = 0;
  for (int g = 0; g < ngroups; ++g) {
    float areg[G];
    #pragma unroll
    for (int j = 0; j < G; ++j) areg[j] = a_lds[cur][j * B_SZ + b];

    if (g + 1 < ngroups) {
      PROJ(cur ^ 1);                    // consume xr (group g+1) -> other buffer
      LOADX(tw + G * (g + 2));          // issue loads for group g+2 (clamped)
    }

    const int tg = tw + G * g;
    #pragma unroll
    for (int j = 0; j < G; ++j) {
      float gz = fmaf(h, w2, areg[j]);
      float u  = __builtin_amdgcn_exp2f(gz);
      float r  = __builtin_amdgcn_rcpf(u + 1.0f);
      h = fmaf(-2.0f, r, 1.0f);         // tanh(z) = 1 - 2/(2^(2*log2e*z)+1)
      const int t = tg + j;
      if (t >= t0 && t < t0 + CHUNK && t < T_LEN)
        out[(size_t)t * B_SZ + b] = fmaf(h, fw, fb);
    }
    __syncthreads();
    cur ^= 1;
  }
}

extern "C" void kernel_launch(void* const* d_in, const int* in_sizes, int n_in,
                              void* d_out, int out_size, void* d_ws, size_t ws_size,
                              hipStream_t stream) {
  const float* x    = (const float*)d_in[0];
  const float* W_ih = (const float*)d_in[1];
  const float* W_hh = (const float*)d_in[2];
  const float* b_ih = (const float*)d_in[3];
  const float* b_hh = (const float*)d_in[4];
  const float* fc_w = (const float*)d_in[5];
  const float* fc_b = (const float*)d_in[6];
  float* out = (float*)d_out;

  rnn_scan_fused<<<NCH, 128, 0, stream>>>(x, W_ih, W_hh, b_ih, b_hh,
                                          fc_w, fc_b, out);
}